// Round 1
// baseline (1135.537 us; speedup 1.0000x reference)
//
#include <hip/hip_runtime.h>

#define HDIM 256
#define MTILE 96
#define APITCH 264   // 256 + 8 pad (shorts) -> 528B row stride, 2-way-free banks
#define PROWS 512
#define RUN 16

typedef __attribute__((ext_vector_type(8))) short short8;
typedef __attribute__((ext_vector_type(4))) short short4v;
typedef __attribute__((ext_vector_type(4))) float floatx4;

__device__ __forceinline__ unsigned short f2bf(float f){
  unsigned u = __float_as_uint(f);
  u += 0x7FFFu + ((u>>16)&1u);          // round-to-nearest-even
  return (unsigned short)(u>>16);
}
// order-preserving float->u32 key for atomicMax
__device__ __forceinline__ unsigned fkey(float f){
  unsigned u = __float_as_uint(f);
  return u ^ ((unsigned)((int)u>>31) | 0x80000000u);
}
__device__ __forceinline__ float fdec(unsigned u){
  unsigned b = (u & 0x80000000u) ? (u & 0x7FFFFFFFu) : ~u;
  return __uint_as_float(b);
}

__global__ void k_zero(float* __restrict__ p, int n){
  int i = blockIdx.x*256 + threadIdx.x;
  if (i < n) p[i] = 0.f;
}

// W1[k][h] fp32 -> W1T[h][k] bf16
__global__ void k_prep(const float* __restrict__ w1, unsigned short* __restrict__ w1t){
  int col = blockIdx.x, k = threadIdx.x;
  w1t[col*HDIM + k] = f2bf(w1[k*HDIM + col]);
}

// s[n] = tanh(x@W1 + b1) @ W2 + b2   via bf16 MFMA, fp32 accum
__launch_bounds__(256, 2)
__global__ void k_scores(const float* __restrict__ x,
                         const unsigned short* __restrict__ w1t,
                         const float* __restrict__ b1,
                         const float* __restrict__ w2,
                         const float* __restrict__ b2,
                         float* __restrict__ s, int n)
{
  __shared__ unsigned short As[MTILE*APITCH];
  __shared__ float sp[4][MTILE];
  const int t = threadIdx.x;
  const int wv = t>>6;
  const int lane = t&63;
  const int l15 = lane&15;
  const int quad = lane>>4;
  const long long node0 = (long long)blockIdx.x * MTILE;

  // B fragments: wave wv owns cols [wv*64, wv*64+64), all K in registers (128 VGPR)
  short8 bf[8][4];
  float b1v[4], w2v[4];
  const int cb = wv*64;
  #pragma unroll
  for (int ct=0; ct<4; ++ct){
    int col = cb + ct*16 + l15;
    b1v[ct] = b1[col];
    w2v[ct] = w2[col];
    #pragma unroll
    for (int kc=0; kc<8; ++kc)
      bf[kc][ct] = *(const short8*)(w1t + (size_t)col*HDIM + kc*32 + quad*8);
  }

  // stage A tile (96 rows x 256 k) fp32->bf16 into LDS, coalesced
  const float4* x4 = (const float4*)x;
  #pragma unroll
  for (int j=0; j<MTILE/4; ++j){
    int f = j*256 + t;
    int row = f>>6, c4 = f&63;
    long long gr = node0 + row;
    float4 v = make_float4(0.f,0.f,0.f,0.f);
    if (gr < n) v = x4[gr*(HDIM/4) + c4];
    short4v p;
    p.x=(short)f2bf(v.x); p.y=(short)f2bf(v.y); p.z=(short)f2bf(v.z); p.w=(short)f2bf(v.w);
    *(short4v*)(As + row*APITCH + c4*4) = p;
  }
  __syncthreads();

  #pragma unroll 1
  for (int rt=0; rt<MTILE/16; ++rt){
    floatx4 acc[4];
    #pragma unroll
    for (int ct=0;ct<4;++ct) acc[ct] = (floatx4){0.f,0.f,0.f,0.f};
    #pragma unroll
    for (int kc=0; kc<8; ++kc){
      short8 a = *(const short8*)(As + (rt*16 + l15)*APITCH + kc*32 + quad*8);
      #pragma unroll
      for (int ct=0; ct<4; ++ct)
        acc[ct] = __builtin_amdgcn_mfma_f32_16x16x32_bf16(a, bf[kc][ct], acc[ct], 0, 0, 0);
    }
    // epilogue: part[r] = sum over this wave's 64 cols of tanh(h+b1)*W2
    float part[4] = {0.f,0.f,0.f,0.f};
    #pragma unroll
    for (int ct=0; ct<4; ++ct){
      #pragma unroll
      for (int r=0; r<4; ++r){
        float h = acc[ct][r] + b1v[ct];
        float z = fminf(fmaxf(2.f*h, -30.f), 30.f);
        float e = __expf(z);
        part[r] += __fdividef(e-1.f, e+1.f) * w2v[ct];   // tanh(h)
      }
    }
    #pragma unroll
    for (int off=8; off>=1; off>>=1){
      #pragma unroll
      for (int r=0;r<4;++r) part[r] += __shfl_xor(part[r], off, 64);
    }
    if (l15==0){
      #pragma unroll
      for (int r=0;r<4;++r) sp[wv][rt*16 + quad*4 + r] = part[r];
    }
  }
  __syncthreads();
  if (t < MTILE){
    long long gr = node0 + t;
    if (gr < n) s[gr] = sp[0][t]+sp[1][t]+sp[2][t]+sp[3][t] + b2[0];
  }
}

__global__ void k_segmax(const float* __restrict__ s, const int* __restrict__ batch,
                         unsigned* __restrict__ segmax_u, float* __restrict__ counts, int n){
  long long i0 = ((long long)(blockIdx.x*256 + threadIdx.x)) * RUN;
  if (i0 >= n) return;
  long long i1 = i0 + RUN; if (i1 > n) i1 = n;
  int curb = batch[i0];
  unsigned cm = 0u; float cnt = 0.f;
  for (long long i=i0;i<i1;++i){
    int b = batch[i];
    if (b != curb){
      atomicMax(&segmax_u[curb], cm);
      atomicAdd(&counts[curb], cnt);
      curb = b; cm = 0u; cnt = 0.f;
    }
    unsigned k = fkey(s[i]);
    cm = cm > k ? cm : k;
    cnt += 1.f;
  }
  atomicMax(&segmax_u[curb], cm);
  atomicAdd(&counts[curb], cnt);
}

// overwrite s with e = exp(s - segmax), accumulate denom
__global__ void k_edenom(float* __restrict__ s, const int* __restrict__ batch,
                         const unsigned* __restrict__ segmax_u, float* __restrict__ denom, int n){
  long long i0 = ((long long)(blockIdx.x*256 + threadIdx.x)) * RUN;
  if (i0 >= n) return;
  long long i1 = i0 + RUN; if (i1 > n) i1 = n;
  int curb = batch[i0];
  float m = fdec(segmax_u[curb]);
  float acc = 0.f;
  for (long long i=i0;i<i1;++i){
    int b = batch[i];
    if (b != curb){
      atomicAdd(&denom[curb], acc);
      curb = b; m = fdec(segmax_u[b]); acc = 0.f;
    }
    float e = __expf(s[i] - m);
    s[i] = e; acc += e;
  }
  atomicAdd(&denom[curb], acc);
}

// mean-sum, max, attn accumulation; thread t owns column t
__launch_bounds__(256)
__global__ void k_pool(const float* __restrict__ x, const int* __restrict__ batch,
                       const float* __restrict__ e, const float* __restrict__ denom,
                       float* __restrict__ sums, unsigned* __restrict__ maxu,
                       float* __restrict__ attn, int n){
  const int t = threadIdx.x;
  long long r0 = (long long)blockIdx.x * PROWS;
  long long r1 = r0 + PROWS; if (r1 > n) r1 = n;
  int curb = batch[r0];
  float rd = 1.f/denom[curb];
  float sum=0.f, att=0.f, mx=-INFINITY;
  for (long long i=r0;i<r1;++i){
    int b = batch[i];
    if (b != curb){
      atomicAdd(&sums[(size_t)curb*HDIM + t], sum);
      atomicAdd(&attn[(size_t)curb*HDIM + t], att);
      atomicMax(&maxu[(size_t)curb*HDIM + t], fkey(mx));
      curb=b; rd = 1.f/denom[b]; sum=0.f; att=0.f; mx=-INFINITY;
    }
    float w = e[i]*rd;
    float v = x[i*HDIM + t];
    sum += v; att += v*w; mx = fmaxf(mx, v);
  }
  atomicAdd(&sums[(size_t)curb*HDIM + t], sum);
  atomicAdd(&attn[(size_t)curb*HDIM + t], att);
  atomicMax(&maxu[(size_t)curb*HDIM + t], fkey(mx));
}

__global__ void k_fin(const float* __restrict__ sums, const unsigned* __restrict__ maxu,
                      const float* __restrict__ attn, const float* __restrict__ counts,
                      float* __restrict__ out, int bcount){
  int idx = blockIdx.x*256 + threadIdx.x;
  int total = bcount*3*HDIM;
  if (idx >= total) return;
  int b = idx / (3*HDIM);
  int c = idx - b*(3*HDIM);
  float cnt = counts[b];
  float v;
  if (c < HDIM)        v = sums[(size_t)b*HDIM + c] / fmaxf(cnt, 1.f);
  else if (c < 2*HDIM) v = (cnt > 0.f) ? fdec(maxu[(size_t)b*HDIM + (c-HDIM)]) : 0.f;
  else                 v = attn[(size_t)b*HDIM + (c-2*HDIM)];
  out[idx] = v;
}

extern "C" void kernel_launch(void* const* d_in, const int* in_sizes, int n_in,
                              void* d_out, int out_size, void* d_ws, size_t ws_size,
                              hipStream_t stream){
  const float* x   = (const float*)d_in[0];
  const int* batch = (const int*)d_in[1];
  const float* W1  = (const float*)d_in[2];
  const float* b1  = (const float*)d_in[3];
  const float* W2  = (const float*)d_in[4];
  const float* b2  = (const float*)d_in[5];
  float* out = (float*)d_out;
  const int n = in_sizes[1];            // N nodes
  const int B = out_size / (3*HDIM);    // graphs

  // workspace layout
  char* w = (char*)d_ws;
  unsigned short* W1T = (unsigned short*)w;
  size_t off = (size_t)HDIM*HDIM*2;
  float* s = (float*)(w + off);
  off += (size_t)((n+3)&~3)*4;
  float* stats = (float*)(w + off);
  unsigned* segmax_u = (unsigned*)stats;
  float* denom  = stats + B;
  float* counts = stats + 2*B;
  float* sums   = stats + 3*B;
  unsigned* maxu = (unsigned*)(stats + 3*B + (size_t)B*HDIM);
  float* attn   = stats + 3*B + 2*(size_t)B*HDIM;
  int statwords = 3*B + 3*B*HDIM;

  hipLaunchKernelGGL(k_zero, dim3((statwords+255)/256), dim3(256), 0, stream, stats, statwords);
  hipLaunchKernelGGL(k_prep, dim3(HDIM), dim3(HDIM), 0, stream, W1, W1T);
  hipLaunchKernelGGL(k_scores, dim3((n+MTILE-1)/MTILE), dim3(256), 0, stream,
                     x, W1T, b1, W2, b2, s, n);
  int thr = (n + RUN - 1)/RUN;
  hipLaunchKernelGGL(k_segmax, dim3((thr+255)/256), dim3(256), 0, stream,
                     s, batch, segmax_u, counts, n);
  hipLaunchKernelGGL(k_edenom, dim3((thr+255)/256), dim3(256), 0, stream,
                     s, batch, segmax_u, denom, n);
  hipLaunchKernelGGL(k_pool, dim3((n+PROWS-1)/PROWS), dim3(256), 0, stream,
                     x, batch, s, denom, sums, maxu, attn, n);
  hipLaunchKernelGGL(k_fin, dim3((out_size+255)/256), dim3(256), 0, stream,
                     sums, maxu, attn, counts, out, B);
}

// Round 2
// 899.626 us; speedup vs baseline: 1.2622x; 1.2622x over previous
//
#include <hip/hip_runtime.h>

#define HDIM 256
#define MTILE 64
#define NITER 4          // row-tiles per scores block (256 rows/block)
#define APITCH 264       // 256 + 8 pad (shorts)
#define PROWS 256
#define CHUNK 16

typedef __attribute__((ext_vector_type(8))) short short8;
typedef __attribute__((ext_vector_type(4))) short short4v;
typedef __attribute__((ext_vector_type(4))) float floatx4;

__device__ __forceinline__ unsigned short f2bf(float f){
  unsigned u = __float_as_uint(f);
  u += 0x7FFFu + ((u>>16)&1u);
  return (unsigned short)(u>>16);
}
__device__ __forceinline__ unsigned fkey(float f){
  unsigned u = __float_as_uint(f);
  return u ^ ((unsigned)((int)u>>31) | 0x80000000u);
}
__device__ __forceinline__ float fdec(unsigned u){
  unsigned b = (u & 0x80000000u) ? (u & 0x7FFFFFFFu) : ~u;
  return __uint_as_float(b);
}

__global__ void k_zero(float* __restrict__ p, int n){
  int i = blockIdx.x*256 + threadIdx.x;
  if (i < n) p[i] = 0.f;
}

__global__ void k_prep(const float* __restrict__ w1, unsigned short* __restrict__ w1t){
  int col = blockIdx.x, k = threadIdx.x;
  w1t[col*HDIM + k] = f2bf(w1[k*HDIM + col]);
}

// segstart[q] for q in [0,B]; every q written exactly once (batch sorted)
__global__ void k_bounds(const int* __restrict__ batch, int* __restrict__ segstart,
                         int n, int B){
  int i = blockIdx.x*256 + threadIdx.x;
  if (i >= n) return;
  int b = batch[i];
  int prev = (i == 0) ? -1 : batch[i-1];
  if (prev != b) for (int q = prev+1; q <= b; ++q) segstart[q] = i;
  if (i == n-1) for (int q = b+1; q <= B; ++q) segstart[q] = n;
}

// s = tanh(x@W1+b1)@W2+b2 via bf16 MFMA; block loops NITER row-tiles
__launch_bounds__(256)
__global__ void k_scores(const float* __restrict__ x,
                         const unsigned short* __restrict__ w1t,
                         const float* __restrict__ b1,
                         const float* __restrict__ w2,
                         const float* __restrict__ b2,
                         float* __restrict__ s, int n)
{
  __shared__ unsigned short As[MTILE*APITCH];
  __shared__ float sp[4][MTILE];
  const int t = threadIdx.x;
  const int wv = t>>6;
  const int lane = t&63;
  const int l15 = lane&15;
  const int quad = lane>>4;
  const long long base = (long long)blockIdx.x * (MTILE*NITER);

  // B fragments: wave wv owns cols [wv*64, wv*64+64), all K in registers
  short8 bf[8][4];
  float b1v[4], w2v[4];
  const int cb = wv*64;
  #pragma unroll
  for (int ct=0; ct<4; ++ct){
    int col = cb + ct*16 + l15;
    b1v[ct] = b1[col];
    w2v[ct] = w2[col];
    #pragma unroll
    for (int kc=0; kc<8; ++kc)
      bf[kc][ct] = *(const short8*)(w1t + (size_t)col*HDIM + kc*32 + quad*8);
  }

  const float4* x4 = (const float4*)x;
  for (int it = 0; it < NITER; ++it){
    const long long node0 = base + (long long)it*MTILE;
    if (node0 >= n) break;

    // stage A tile (64 rows x 256 k) fp32->bf16 into LDS, coalesced
    #pragma unroll
    for (int j=0; j<MTILE/4; ++j){
      int f = j*256 + t;
      int row = f>>6, c4 = f&63;
      long long gr = node0 + row;
      float4 v = make_float4(0.f,0.f,0.f,0.f);
      if (gr < n) v = x4[gr*(HDIM/4) + c4];
      short4v p;
      p.x=(short)f2bf(v.x); p.y=(short)f2bf(v.y); p.z=(short)f2bf(v.z); p.w=(short)f2bf(v.w);
      *(short4v*)(As + row*APITCH + c4*4) = p;
    }
    __syncthreads();

    #pragma unroll 1
    for (int rt=0; rt<MTILE/16; ++rt){
      floatx4 acc[4];
      #pragma unroll
      for (int ct=0;ct<4;++ct) acc[ct] = (floatx4){0.f,0.f,0.f,0.f};
      #pragma unroll
      for (int kc=0; kc<8; ++kc){
        short8 a = *(const short8*)(As + (rt*16 + l15)*APITCH + kc*32 + quad*8);
        #pragma unroll
        for (int ct=0; ct<4; ++ct)
          acc[ct] = __builtin_amdgcn_mfma_f32_16x16x32_bf16(a, bf[kc][ct], acc[ct], 0, 0, 0);
      }
      float part[4] = {0.f,0.f,0.f,0.f};
      #pragma unroll
      for (int ct=0; ct<4; ++ct){
        #pragma unroll
        for (int r=0; r<4; ++r){
          float h = acc[ct][r] + b1v[ct];
          float z = fminf(fmaxf(2.f*h, -30.f), 30.f);
          float e = __expf(z);
          part[r] += __fdividef(e-1.f, e+1.f) * w2v[ct];
        }
      }
      #pragma unroll
      for (int off=8; off>=1; off>>=1){
        #pragma unroll
        for (int r=0;r<4;++r) part[r] += __shfl_xor(part[r], off, 64);
      }
      if (l15==0){
        #pragma unroll
        for (int r=0;r<4;++r) sp[wv][rt*16 + quad*4 + r] = part[r];
      }
    }
    __syncthreads();
    if (t < MTILE){
      long long gr = node0 + t;
      if (gr < n) s[gr] = sp[0][t]+sp[1][t]+sp[2][t]+sp[3][t] + b2[0];
    }
    // barrier before next iteration overwrites As (s-write reads sp, staging writes As;
    // sp rewrite in next compute phase is ordered by the post-staging barrier)
  }
}

// per-segment: max, e=exp(s-m) in place, denom, counts. grid = B blocks.
__global__ void k_seg(float* __restrict__ s, const int* __restrict__ segstart,
                      float* __restrict__ denom, float* __restrict__ counts){
  __shared__ float red[4];
  const int b = blockIdx.x;
  const int t = threadIdx.x;
  const int lane = t&63, wv = t>>6;
  const int start = segstart[b], end = segstart[b+1];

  float m = -INFINITY;
  for (int i = start + t; i < end; i += 256) m = fmaxf(m, s[i]);
  #pragma unroll
  for (int off=32; off>=1; off>>=1) m = fmaxf(m, __shfl_xor(m, off, 64));
  if (lane==0) red[wv] = m;
  __syncthreads();
  m = fmaxf(fmaxf(red[0],red[1]), fmaxf(red[2],red[3]));

  float acc = 0.f;
  for (int i = start + t; i < end; i += 256){
    float e = __expf(s[i] - m);
    s[i] = e; acc += e;
  }
  #pragma unroll
  for (int off=32; off>=1; off>>=1) acc += __shfl_xor(acc, off, 64);
  __syncthreads();
  if (lane==0) red[wv] = acc;
  __syncthreads();
  if (t==0){
    float total = red[0]+red[1]+red[2]+red[3];
    denom[b] = (total > 0.f) ? total : 1.f;
    counts[b] = (float)(end - start);
  }
}

// pooling: thread t owns column t; 16-row unrolled fast path
__launch_bounds__(256)
__global__ void k_pool(const float* __restrict__ x, const int* __restrict__ batch,
                       const float* __restrict__ e, const float* __restrict__ denom,
                       float* __restrict__ sums, unsigned* __restrict__ maxu,
                       float* __restrict__ attn, int n){
  const int t = threadIdx.x;
  long long r0 = (long long)blockIdx.x * PROWS;
  if (r0 >= n) return;
  long long r1 = r0 + PROWS; if (r1 > n) r1 = n;
  int curb = batch[r0];
  float rd = 1.f/denom[curb];
  float sum=0.f, att=0.f, mx=-INFINITY;
  long long i = r0;
  while (i < r1){
    if (i + CHUNK <= r1 && batch[i + CHUNK - 1] == curb){
      float v[CHUNK], w[CHUNK];
      #pragma unroll
      for (int k=0;k<CHUNK;++k) v[k] = x[(i+k)*HDIM + t];
      #pragma unroll
      for (int k=0;k<CHUNK;++k) w[k] = e[i+k];
      #pragma unroll
      for (int k=0;k<CHUNK;++k){
        sum += v[k];
        att += v[k]*(w[k]*rd);
        mx = fmaxf(mx, v[k]);
      }
      i += CHUNK;
    } else {
      int b = batch[i];
      if (b != curb){
        atomicAdd(&sums[(size_t)curb*HDIM + t], sum);
        atomicAdd(&attn[(size_t)curb*HDIM + t], att);
        atomicMax(&maxu[(size_t)curb*HDIM + t], fkey(mx));
        curb=b; rd = 1.f/denom[b]; sum=0.f; att=0.f; mx=-INFINITY;
      }
      float v = x[i*HDIM + t];
      sum += v; att += v*(e[i]*rd); mx = fmaxf(mx, v);
      ++i;
    }
  }
  atomicAdd(&sums[(size_t)curb*HDIM + t], sum);
  atomicAdd(&attn[(size_t)curb*HDIM + t], att);
  atomicMax(&maxu[(size_t)curb*HDIM + t], fkey(mx));
}

__global__ void k_fin(const float* __restrict__ sums, const unsigned* __restrict__ maxu,
                      const float* __restrict__ attn, const float* __restrict__ counts,
                      float* __restrict__ out, int bcount){
  int idx = blockIdx.x*256 + threadIdx.x;
  int total = bcount*3*HDIM;
  if (idx >= total) return;
  int b = idx / (3*HDIM);
  int c = idx - b*(3*HDIM);
  float cnt = counts[b];
  float v;
  if (c < HDIM)        v = sums[(size_t)b*HDIM + c] / fmaxf(cnt, 1.f);
  else if (c < 2*HDIM) v = (cnt > 0.f) ? fdec(maxu[(size_t)b*HDIM + (c-HDIM)]) : 0.f;
  else                 v = attn[(size_t)b*HDIM + (c-2*HDIM)];
  out[idx] = v;
}

extern "C" void kernel_launch(void* const* d_in, const int* in_sizes, int n_in,
                              void* d_out, int out_size, void* d_ws, size_t ws_size,
                              hipStream_t stream){
  const float* x   = (const float*)d_in[0];
  const int* batch = (const int*)d_in[1];
  const float* W1  = (const float*)d_in[2];
  const float* b1  = (const float*)d_in[3];
  const float* W2  = (const float*)d_in[4];
  const float* b2  = (const float*)d_in[5];
  float* out = (float*)d_out;
  const int n = in_sizes[1];
  const int B = out_size / (3*HDIM);

  char* w = (char*)d_ws;
  unsigned short* W1T = (unsigned short*)w;
  size_t off = (size_t)HDIM*HDIM*2;
  float* s = (float*)(w + off);
  off += (size_t)((n+3)&~3)*4;
  int* segstart = (int*)(w + off);
  off += (size_t)((B+4)&~3)*4;
  float* stats = (float*)(w + off);
  float* denom  = stats;
  float* counts = stats + B;
  float* sums   = stats + 2*B;
  unsigned* maxu = (unsigned*)(stats + 2*B + (size_t)B*HDIM);
  float* attn   = stats + 2*B + 2*(size_t)B*HDIM;
  int zerowords = 3*B*HDIM;

  hipLaunchKernelGGL(k_zero, dim3((zerowords+255)/256), dim3(256), 0, stream, sums, zerowords);
  hipLaunchKernelGGL(k_prep, dim3(HDIM), dim3(HDIM), 0, stream, W1, W1T);
  hipLaunchKernelGGL(k_bounds, dim3((n+255)/256), dim3(256), 0, stream, batch, segstart, n, B);
  hipLaunchKernelGGL(k_scores, dim3((n + MTILE*NITER - 1)/(MTILE*NITER)), dim3(256), 0, stream,
                     x, W1T, b1, W2, b2, s, n);
  hipLaunchKernelGGL(k_seg, dim3(B), dim3(256), 0, stream, s, segstart, denom, counts);
  hipLaunchKernelGGL(k_pool, dim3((n+PROWS-1)/PROWS), dim3(256), 0, stream,
                     x, batch, s, denom, sums, maxu, attn, n);
  hipLaunchKernelGGL(k_fin, dim3((out_size+255)/256), dim3(256), 0, stream,
                     sums, maxu, attn, counts, out, B);
}